// Round 22
// baseline (7454.449 us; speedup 1.0000x reference)
//
#include <hip/hip_runtime.h>
#include <hip/hip_bf16.h>

// ---------------- constants ----------------
static constexpr int kT    = 2048;
static constexpr int kOUT_ELEMS = 2048 * 4096;   // output 0 size

typedef _Float16 half2_t __attribute__((ext_vector_type(2)));
typedef _Float16 half8_t __attribute__((ext_vector_type(8)));
typedef float f32x4_t __attribute__((ext_vector_type(4)));
typedef unsigned long long u64;

__device__ __forceinline__ unsigned pack_h2(float a, float b) {
  half2_t h{(_Float16)a, (_Float16)b};
  return __builtin_bit_cast(unsigned, h);
}
__device__ __forceinline__ float fdot2u(unsigned a, unsigned b, float c) {
  return __builtin_amdgcn_fdot2(__builtin_bit_cast(half2_t, a),
                                __builtin_bit_cast(half2_t, b), c, false);
}
__device__ __forceinline__ float sigm(float x) {
  return 1.f / (1.f + __expf(-x));
}
__device__ __forceinline__ float tanh_f(float x) {
  float ax = fabsf(x);
  float e = __expf(-2.f * ax);
  float r = (1.f - e) / (1.f + e);
  return x < 0.f ? -r : r;
}

// ---------------- K0: prep ----------------
__global__ __launch_bounds__(256) void prep_kernel(
    const float* __restrict__ c_in,
    const float* __restrict__ enc_Wih, const float* __restrict__ enc_bih,
    const float* __restrict__ cenc_Wih, const float* __restrict__ cenc_bih,
    const float* __restrict__ enc_Whh, const float* __restrict__ cenc_Whh,
    const float* __restrict__ l0_Wih, const float* __restrict__ l0_Whh,
    const float* __restrict__ l1_Wih, const float* __restrict__ l1_Whh,
    const float* __restrict__ out_W,
    const float* __restrict__ l0_bih, const float* __restrict__ l0_bhh,
    const float* __restrict__ l1_bih, const float* __restrict__ l1_bhh,
    float* __restrict__ bcat,
    float* __restrict__ bias0, float* __restrict__ bias1,
    unsigned* __restrict__ wprep5, unsigned* __restrict__ wgru,
    u64* __restrict__ payz,
    _Float16* __restrict__ c16, _Float16* __restrict__ wcat16,
    _Float16* __restrict__ l0W16, _Float16* __restrict__ l1W16,
    _Float16* __restrict__ outW16) {
  int idx0 = blockIdx.x * blockDim.x + threadIdx.x;
  int stride = gridDim.x * blockDim.x;
  for (int i = idx0; i < 1024; i += stride) payz[i] = 0ull;   // re-zero every launch
  for (int i = idx0; i < 768; i += stride)
    bcat[i] = (i < 384) ? enc_bih[i] : cenc_bih[i - 384];
  for (int i = idx0; i < 2048; i += stride) {
    bias0[i] = l0_bih[i] + l0_bhh[i];
    bias1[i] = l1_bih[i] + l1_bhh[i];
  }
  for (int i = idx0; i < 4 * 4 * 128 * 256; i += stride) {
    int j = i & 255;
    int e = (i >> 8) & 127;
    int p = (i >> 15) & 3;
    int ld = i >> 17;  // layer*2 + dir
    const float* W = (ld < 2 ? l0_Whh : l1_Whh) + (ld & 1) * 1024 * 256;
    int gate = j >> 6, m = j & 63;
    int R = gate * 256 + 64 * p + m;
    wprep5[i] = pack_h2(W[R * 256 + 2 * e], W[R * 256 + 2 * e + 1]);
  }
  for (int i = idx0; i < 2 * 64 * 384; i += stride) {
    int row = i % 384;
    int e = (i / 384) & 63;
    int g2 = i / (64 * 384);
    const float* W = g2 ? cenc_Whh : enc_Whh;   // dir0 at base
    wgru[i] = pack_h2(W[row * 128 + 2 * e], W[row * 128 + 2 * e + 1]);
  }
  // fp16 copies for MFMA GEMMs
  for (int i = idx0; i < 2048 * 1024; i += stride) c16[i] = (_Float16)c_in[i];
  for (int i = idx0; i < 768 * 1024; i += stride) {
    int r = i >> 10, cc = i & 1023;
    float v = (r < 384) ? enc_Wih[r * 1024 + cc] : cenc_Wih[(r - 384) * 1024 + cc];
    wcat16[i] = (_Float16)v;
  }
  for (int i = idx0; i < 2048 * 1024; i += stride) l0W16[i] = (_Float16)l0_Wih[i];
  for (int i = idx0; i < 2048 * 512; i += stride)  l1W16[i] = (_Float16)l1_Wih[i];
  for (int i = idx0; i < 4096 * 512; i += stride)  outW16[i] = (_Float16)out_W[i];
}

// ---------------- MFMA GEMM body: C[M][N] = A[M][K] * B[N][K]^T + bias[N] ----------------
// Threads [0,256) of the calling block; barrier-free.
__device__ __forceinline__ void gemm_body(
    const _Float16* __restrict__ A, const _Float16* __restrict__ B,
    const float* __restrict__ bias, float* __restrict__ C,
    int N, int K, int bx, int by, int tid) {
  const int wave = tid >> 6, lane = tid & 63;
  const int r = lane & 15, kg = lane >> 4;
  const int m0 = by * 64 + wave * 16;
  const int n0 = bx * 64;
  const _Float16* ap = A + (size_t)(m0 + r) * K + kg * 8;
  const _Float16* bp = B + (size_t)(n0 + r) * K + kg * 8;
  f32x4_t acc0 = {0.f, 0.f, 0.f, 0.f};
  f32x4_t acc1 = {0.f, 0.f, 0.f, 0.f};
  f32x4_t acc2 = {0.f, 0.f, 0.f, 0.f};
  f32x4_t acc3 = {0.f, 0.f, 0.f, 0.f};
  for (int k0 = 0; k0 < K; k0 += 32) {
    half8_t av = *(const half8_t*)(ap + k0);
    half8_t b0 = *(const half8_t*)(bp + k0);
    half8_t b1 = *(const half8_t*)(bp + (size_t)16 * K + k0);
    half8_t b2 = *(const half8_t*)(bp + (size_t)32 * K + k0);
    half8_t b3 = *(const half8_t*)(bp + (size_t)48 * K + k0);
    acc0 = __builtin_amdgcn_mfma_f32_16x16x32_f16(av, b0, acc0, 0, 0, 0);
    acc1 = __builtin_amdgcn_mfma_f32_16x16x32_f16(av, b1, acc1, 0, 0, 0);
    acc2 = __builtin_amdgcn_mfma_f32_16x16x32_f16(av, b2, acc2, 0, 0, 0);
    acc3 = __builtin_amdgcn_mfma_f32_16x16x32_f16(av, b3, acc3, 0, 0, 0);
  }
  float bv0 = bias ? bias[n0 + r]      : 0.f;
  float bv1 = bias ? bias[n0 + 16 + r] : 0.f;
  float bv2 = bias ? bias[n0 + 32 + r] : 0.f;
  float bv3 = bias ? bias[n0 + 48 + r] : 0.f;
  const int row0 = m0 + 4 * kg;
#pragma unroll
  for (int i = 0; i < 4; ++i) {
    float* cr = C + (size_t)(row0 + i) * N + n0 + r;
    cr[0]  = acc0[i] + bv0;
    cr[16] = acc1[i] + bv1;
    cr[32] = acc2[i] + bv2;
    cr[48] = acc3[i] + bv3;
  }
}

__global__ __launch_bounds__(256) void gemm_mfma(
    const _Float16* __restrict__ A, const _Float16* __restrict__ B,
    const float* __restrict__ bias, float* __restrict__ C,
    int M, int N, int K) {
  gemm_body(A, B, bias, C, N, K, blockIdx.x, blockIdx.y, threadIdx.x);
}

// ---------------- fused: GRU chains (blocks 0..3) + cW GEMM (blocks 4..) ----------------
// 384 threads. GRU part: gate=j>>7 (0:r 1:z 2:n), m=j&127; 40 VGPR + 24 LDS weights.
// GEMM part: threads <256 run the barrier-free MFMA body (grid 32x32 tiles of cW).
__global__ __launch_bounds__(384) void gru_gemm(
    const float* __restrict__ xgg,   // [T][768]
    const float* __restrict__ c_in,  // [T][1024]
    const unsigned* __restrict__ wgru,
    const float* __restrict__ enc_Wih, const float* __restrict__ enc_bih,
    const float* __restrict__ enc_bhh,
    const float* __restrict__ cenc_Wih, const float* __restrict__ cenc_bih,
    const float* __restrict__ cenc_bhh,
    float* __restrict__ u_out, float* __restrict__ cmem_out,
    const _Float16* __restrict__ c16, const _Float16* __restrict__ l0W16,
    const float* __restrict__ bias0, float* __restrict__ cW) {
  const int b = blockIdx.x, j = threadIdx.x;
  __shared__ __align__(16) unsigned h2g[64];
  __shared__ float rv[128], zv[128];
  __shared__ __align__(16) unsigned wl[384 * 26];  // 39936 B
  if (b >= 4) {
    if (j < 256) {
      int gb = b - 4;                  // 0..1023 -> 32x32 tiles
      gemm_body(c16, l0W16, bias0, cW, 2048, 1024, gb & 31, gb >> 5, j);
    }
    return;
  }
  const int gate = j >> 7, m = j & 127;
  if (b < 2) {
    const unsigned* wg = wgru + b * (64 * 384);
    const float* bhh = b ? cenc_bhh : enc_bhh;
    unsigned wv[40];
#pragma unroll
    for (int e = 0; e < 40; ++e) wv[e] = wg[e * 384 + j];
#pragma unroll
    for (int e2 = 0; e2 < 24; ++e2) wl[j * 26 + e2] = wg[(40 + e2) * 384 + j];
    const float bh = bhh[j];
    if (j < 64) h2g[j] = 0u;
    float hreg = 0.f;
    __syncthreads();
    const float* xp = xgg + b * 384 + j;
    float xc = xp[0];
    for (int t = 0; t < kT; ++t) {
      float xn = 0.f;
      if (t + 1 < kT) xn = xp[(t + 1) * 768];
      const uint4* h4 = (const uint4*)h2g;
      float a = 0.f;
#pragma unroll
      for (int k = 0; k < 10; ++k) {
        uint4 hh = h4[k];
        a = fdot2u(wv[4 * k + 0], hh.x, a);
        a = fdot2u(wv[4 * k + 1], hh.y, a);
        a = fdot2u(wv[4 * k + 2], hh.z, a);
        a = fdot2u(wv[4 * k + 3], hh.w, a);
      }
#pragma unroll
      for (int k = 0; k < 6; ++k) {
        uint4 hh = h4[10 + k];
        uint4 qw = *(const uint4*)&wl[j * 26 + 4 * k];
        a = fdot2u(qw.x, hh.x, a);
        a = fdot2u(qw.y, hh.y, a);
        a = fdot2u(qw.z, hh.z, a);
        a = fdot2u(qw.w, hh.w, a);
      }
      if (gate == 0)      rv[m] = sigm(xc + a + bh);
      else if (gate == 1) zv[m] = sigm(xc + a + bh);
      __syncthreads();
      if (gate == 2) {
        float r = rv[m], z = zv[m];
        float n = tanh_f(xc + r * (a + bh));
        hreg = (1.f - z) * n + z * hreg;
        float hx = __shfl_xor(hreg, 1);
        if (!(m & 1)) h2g[m >> 1] = pack_h2(hreg, hx);
      }
      __syncthreads();
      xc = xn;
    }
    if (gate == 2) { if (b == 0) u_out[m] = hreg; else cmem_out[m] = hreg; }
  } else {
    // backward direction: single step from zero state at t = T-1
    const float* Wih = ((b == 2) ? enc_Wih : cenc_Wih) + 384 * 1024;
    const float* bih = ((b == 2) ? enc_bih : cenc_bih) + 384;
    const float* bhh = ((b == 2) ? enc_bhh : cenc_bhh) + 384;
    const float* crow = c_in + (long)(kT - 1) * 1024;
    float a = bih[j];
    const float* wr = Wih + (long)j * 1024;
    for (int k = 0; k < 1024; k += 4) {
      float4 cv = *(const float4*)&crow[k];
      float4 wv4 = *(const float4*)&wr[k];
      a += cv.x * wv4.x + cv.y * wv4.y + cv.z * wv4.z + cv.w * wv4.w;
    }
    const float bh = bhh[j];
    if (gate == 0)      rv[m] = sigm(a + bh);
    else if (gate == 1) zv[m] = sigm(a + bh);
    __syncthreads();
    if (gate == 2) {
      float r = rv[m], z = zv[m];
      float n = tanh_f(a + r * bh);
      float h = (1.f - z) * n;
      if (b == 2) u_out[128 + m] = h; else cmem_out[128 + m] = h;
    }
  }
}

// ---------------- attention ----------------
__global__ __launch_bounds__(256) void attn_dots(
    const float* __restrict__ mem, const float* __restrict__ u, float* __restrict__ d) {
  __shared__ float us[256];
  int tid = threadIdx.x;
  us[tid] = u[tid];
  __syncthreads();
  int g = tid >> 3, l8 = tid & 7;
  int row = blockIdx.x * 32 + g;
  const float* mr = mem + (long)row * 256 + l8 * 32;
  float p = 0.f;
#pragma unroll
  for (int k = 0; k < 32; k += 4) {
    float4 m4 = *(const float4*)&mr[k];
    p += m4.x * us[l8 * 32 + k] + m4.y * us[l8 * 32 + k + 1] +
         m4.z * us[l8 * 32 + k + 2] + m4.w * us[l8 * 32 + k + 3];
  }
  p += __shfl_down(p, 4);
  p += __shfl_down(p, 2);
  p += __shfl_down(p, 1);
  if (l8 == 0) d[row] = p;
}

__global__ __launch_bounds__(1024) void attn_soft(
    const float* __restrict__ d, float* __restrict__ p, float* __restrict__ h_acc) {
  __shared__ float red[1024];
  int tid = threadIdx.x;
  float v[8];
  float mx = -1e30f;
#pragma unroll
  for (int i = 0; i < 8; i++) { v[i] = d[tid * 8 + i]; mx = fmaxf(mx, v[i]); }
  red[tid] = mx; __syncthreads();
  for (int s = 512; s > 0; s >>= 1) {
    if (tid < s) red[tid] = fmaxf(red[tid], red[tid + s]);
    __syncthreads();
  }
  mx = red[0]; __syncthreads();
  float sm = 0.f; float e[8];
#pragma unroll
  for (int i = 0; i < 8; i++) { e[i] = __expf(v[i] - mx); sm += e[i]; }
  red[tid] = sm; __syncthreads();
  for (int s = 512; s > 0; s >>= 1) {
    if (tid < s) red[tid] += red[tid + s];
    __syncthreads();
  }
  float rz = 1.f / red[0];
#pragma unroll
  for (int i = 0; i < 8; i++) p[tid * 8 + i] = e[i] * rz;
  if (tid < 256) h_acc[tid] = 0.f;
}

__global__ __launch_bounds__(256) void attn_h(
    const float* __restrict__ mem, const float* __restrict__ p, float* __restrict__ h_acc) {
  int tid = threadIdx.x;
  int r0 = blockIdx.x * 128;
  float acc = 0.f;
  for (int i = 0; i < 128; i++) acc += p[r0 + i] * mem[(long)(r0 + i) * 256 + tid];
  atomicAdd(&h_acc[tid], acc);
}

__global__ __launch_bounds__(128) void attn_o(
    const float* __restrict__ u, const float* __restrict__ h_acc,
    const float* __restrict__ know_W, const float* __restrict__ know_b,
    float* __restrict__ o) {
  __shared__ float uh[256];
  int tid = threadIdx.x;
  uh[tid] = u[tid] + h_acc[tid];
  uh[128 + tid] = u[128 + tid] + h_acc[128 + tid];
  __syncthreads();
  int row = blockIdx.x * 128 + tid;
  float acc = know_b[row];
  for (int k = 0; k < 256; k += 4) {
    float4 w4 = *(const float4*)&know_W[row * 256 + k];
    acc += w4.x * uh[k] + w4.y * uh[k + 1] + w4.z * uh[k + 2] + w4.w * uh[k + 3];
  }
  o[row] = acc;
}

__global__ __launch_bounds__(128) void attn_ov(
    const float* __restrict__ o, const float* __restrict__ Wih0, float* __restrict__ ov) {
  int row = blockIdx.x * 128 + threadIdx.x;
  float acc = 0.f;
  for (int k = 0; k < 1024; k += 4) {
    float4 w4 = *(const float4*)&Wih0[(long)row * 1024 + k];
    float4 o4 = *(const float4*)&o[k];
    acc += w4.x * o4.x + w4.y * o4.y + w4.z * o4.z + w4.w * o4.w;
  }
  ov[row] = acc;
}

// ---------------- LSTM (R17 structure; fp16 output) ----------------
__global__ __launch_bounds__(256) void lstm_cc4(
    const unsigned* __restrict__ wp5,    // layer base: [dir<2][p<4][e<128][j<256]
    const float* __restrict__ xg,        // [T][2048] (biases folded)
    const float* __restrict__ extra,     // [2048] rank-1 add or nullptr
    _Float16* __restrict__ out16,        // [T][512] fp16 (feeds next MFMA GEMM)
    u64* __restrict__ pay) {             // layer base: [dir*4+p][slot<2][32] u64
  const int bid = blockIdx.x;
  const int xs = bid & 7;
  if (xs >= 2) return;                   // inactive filler blocks
  const int dir = xs, p = bid >> 3;      // p in [0,4)
  const int j = threadIdx.x;             // [0,256)
  const int gate = j >> 6;
  const int m = j & 63;
  const int R = gate * 256 + 64 * p + m; // global gate row

  __shared__ __align__(16) unsigned h2v[128];      // full h packed (h2)
  __shared__ float gact[256];

  const unsigned* base = wp5 + (size_t)dir * 131072 + (size_t)p * 32768;
  unsigned wv[128];
#pragma unroll
  for (int e = 0; e < 128; ++e) wv[e] = base[e * 256 + j];
#pragma unroll
  for (int e = 0; e < 128; ++e) asm volatile("" : "+v"(wv[e]));

  float exv = extra ? extra[dir * 1024 + R] : 0.f;
  if (j < 128) h2v[j] = 0u;
  float cst = 0.f;
  __syncthreads();

  const int bi = dir * 4 + p;
  u64* mypay = pay + bi * 64;
  const int pi = (j < 96) ? (j >> 5) : 0;
  const int pp = pi + (pi >= p ? 1 : 0);
  u64* peerpay = pay + (dir * 4 + pp) * 64;
  const int pidx = j & 31;

  const float* xp = xg + dir * 1024;
  const int t0 = dir ? (kT - 1) : 0;
  const int dt = dir ? -1 : 1;
  float xc = xp[(long)t0 * 2048 + R] + exv;

  for (int s = 0; s < kT; ++s) {
    const int t = t0 + s * dt;
    float xn_ = 0.f;
    if (s + 1 < kT) xn_ = xp[(long)(t + dt) * 2048 + R];
    if (j < 96 && s > 0) {
      u64 v;
      int guard = 0;
      do {
        v = __hip_atomic_load(&peerpay[(s & 1) * 32 + pidx],
                              __ATOMIC_RELAXED, __HIP_MEMORY_SCOPE_AGENT);
      } while ((unsigned)(v >> 32) < (unsigned)s && ++guard < (1 << 18));
      h2v[32 * pp + pidx] = (unsigned)v;
    }
    __syncthreads();
    const uint4* h4 = (const uint4*)h2v;
    float acc = xc;
#pragma unroll
    for (int c = 0; c < 32; ++c) {
      uint4 hh = h4[c];
      acc = fdot2u(wv[4 * c + 0], hh.x, acc);
      acc = fdot2u(wv[4 * c + 1], hh.y, acc);
      acc = fdot2u(wv[4 * c + 2], hh.z, acc);
      acc = fdot2u(wv[4 * c + 3], hh.w, acc);
    }
    float act = (gate == 2) ? tanh_f(acc) : sigm(acc);
    gact[j] = act;
    __syncthreads();
    if (j < 64) {
      float iv  = gact[j];
      float fv  = gact[64 + j];
      float gv  = gact[128 + j];
      float ovv = gact[192 + j];
      cst = fv * cst + iv * gv;
      float h = ovv * tanh_f(cst);
      out16[(long)t * 512 + dir * 256 + 64 * p + j] = (_Float16)h;
      float hx = __shfl_xor(h, 1);
      if (!(j & 1)) {
        int idx = j >> 1;
        unsigned hp = pack_h2(h, hx);
        h2v[32 * p + idx] = hp;
        u64 tagged = ((u64)(unsigned)(s + 1) << 32) | (u64)hp;
        __hip_atomic_store(&mypay[((s + 1) & 1) * 32 + idx], tagged,
                           __ATOMIC_RELAXED, __HIP_MEMORY_SCOPE_AGENT);
      }
    }
    xc = xn_ + exv;
  }
}

// ---------------- final row softmax ----------------
__global__ __launch_bounds__(256) void softmax_rows(
    const float* __restrict__ logits, float* __restrict__ outp) {
  int t = blockIdx.x, tid = threadIdx.x;
  __shared__ float red[256];
  const float* lr = logits + (long)t * 4096;
  float v[16];
  float mx = -1e30f;
#pragma unroll
  for (int i = 0; i < 16; i++) { v[i] = lr[tid + 256 * i]; mx = fmaxf(mx, v[i]); }
  red[tid] = mx; __syncthreads();
  for (int s = 128; s > 0; s >>= 1) {
    if (tid < s) red[tid] = fmaxf(red[tid], red[tid + s]);
    __syncthreads();
  }
  mx = red[0]; __syncthreads();
  float sm = 0.f;
#pragma unroll
  for (int i = 0; i < 16; i++) { v[i] = __expf(v[i] - mx); sm += v[i]; }
  red[tid] = sm; __syncthreads();
  for (int s = 128; s > 0; s >>= 1) {
    if (tid < s) red[tid] += red[tid + s];
    __syncthreads();
  }
  float rz = 1.f / red[0];
#pragma unroll
  for (int i = 0; i < 16; i++) outp[(long)t * 4096 + tid + 256 * i] = v[i] * rz;
}

// ---------------- launch ----------------
extern "C" void kernel_launch(void* const* d_in, const int* in_sizes, int n_in,
                              void* d_out, int out_size, void* d_ws, size_t ws_size,
                              hipStream_t stream) {
  const float* c        = (const float*)d_in[0];
  const float* memory   = (const float*)d_in[1];
  const float* enc_Wih  = (const float*)d_in[2];
  const float* enc_Whh  = (const float*)d_in[3];
  const float* enc_bih  = (const float*)d_in[4];
  const float* enc_bhh  = (const float*)d_in[5];
  const float* cenc_Wih = (const float*)d_in[6];
  const float* cenc_Whh = (const float*)d_in[7];
  const float* cenc_bih = (const float*)d_in[8];
  const float* cenc_bhh = (const float*)d_in[9];
  const float* know_W   = (const float*)d_in[10];
  const float* know_b   = (const float*)d_in[11];
  const float* l0_Wih   = (const float*)d_in[12];
  const float* l0_Whh   = (const float*)d_in[13];
  const float* l0_bih   = (const float*)d_in[14];
  const float* l0_bhh   = (const float*)d_in[15];
  const float* l1_Wih   = (const float*)d_in[16];
  const float* l1_Whh   = (const float*)d_in[17];
  const float* l1_bih   = (const float*)d_in[18];
  const float* l1_bhh   = (const float*)d_in[19];
  const float* out_W    = (const float*)d_in[20];
  const float* out_b    = (const float*)d_in[21];

  float* ws = (float*)d_ws;
  float* outp = (float*)d_out;

  float* xgg   = ws;                  // 1,572,864   [T][768]
  float* cW    = ws + 1572864;        // 4,194,304   [T][2048] (ends 5,767,168)
  _Float16* l0out16 = (_Float16*)(ws + 5767168);  // 524,288 floats (old wcat slot);
                                                  // dead before gemm4 writes logits
  float* xg1   = ws + 7602176;        // 4,194,304   [T][2048]
  unsigned* wprep5 = (unsigned*)(ws + 11796480);  // 524,288 u32
  float* bcat  = ws + 12320768;       // 768
  float* bias0 = ws + 12321536;       // 2048
  float* bias1 = ws + 12323584;       // 2048
  float* u_vec = ws + 12325632;       // 256
  float* d_att = ws + 12325888;       // 8192
  float* p_att = ws + 12334080;       // 8192
  float* h_acc = ws + 12342272;       // 256
  float* o_vec = ws + 12342528;       // 1024
  float* ov    = ws + 12343552;       // 2048
  unsigned* wgru = (unsigned*)(ws + 13656320);      // 49,152 u32
  u64* payload = (u64*)(ws + 13705472);             // 1024 u64 (ends 13,707,520)
  float* logits = ws;                 // 8,388,608   aliases [0, 8.39M): all dead by gemm4

  // fp16 buffers (aliased where temporally safe):
  _Float16* c16     = (_Float16*)(ws + 12345600);  // 1,048,576 floats; dead after gru_gemm
  _Float16* l1out16 = (_Float16*)(ws + 12345600);  // reuses c16 space (c16 dead); outside logits
  _Float16* wcat16  = (_Float16*)(ws + 7602176);   // in xg1: dead until gemm3 writes xg1
  _Float16* l0W16   = (_Float16*)(ws + 7995392);   // in xg1: used in gru_gemm < gemm3
  _Float16* l1W16   = (_Float16*)(ws + 13707520);  // 524,288 floats
  _Float16* outW16  = (_Float16*)(ws + 14231808);  // 1,048,576 floats (end 15,280,384)

  prep_kernel<<<512, 256, 0, stream>>>(c, enc_Wih, enc_bih, cenc_Wih, cenc_bih,
                                       enc_Whh, cenc_Whh,
                                       l0_Wih, l0_Whh, l1_Wih, l1_Whh, out_W,
                                       l0_bih, l0_bhh, l1_bih, l1_bhh,
                                       bcat, bias0, bias1, wprep5, wgru, payload,
                                       c16, wcat16, l0W16, l1W16, outW16);
  gemm_mfma<<<dim3(12, 32), 256, 0, stream>>>(c16, wcat16, bcat, xgg, 2048, 768, 1024);
  // fused: GRU chains (blocks 0..3) + cW = c @ l0_Wih^T + bias0 (blocks 4..1027)
  gru_gemm<<<1028, 384, 0, stream>>>(xgg, c, wgru, enc_Wih, enc_bih, enc_bhh,
                                     cenc_Wih, cenc_bih, cenc_bhh,
                                     u_vec, outp + kOUT_ELEMS,
                                     c16, l0W16, bias0, cW);
  attn_dots<<<256, 256, 0, stream>>>(memory, u_vec, d_att);
  attn_soft<<<1, 1024, 0, stream>>>(d_att, p_att, h_acc);
  attn_h<<<64, 256, 0, stream>>>(memory, p_att, h_acc);
  attn_o<<<8, 128, 0, stream>>>(u_vec, h_acc, know_W, know_b, o_vec);
  attn_ov<<<16, 128, 0, stream>>>(o_vec, l0_Wih, ov);
  lstm_cc4<<<32, 256, 0, stream>>>(wprep5, cW, ov, l0out16, payload);
  gemm_mfma<<<dim3(32, 32), 256, 0, stream>>>(l0out16, l1W16, bias1, xg1, 2048, 2048, 512);
  lstm_cc4<<<32, 256, 0, stream>>>(wprep5 + 262144, xg1, nullptr, l1out16, payload + 512);
  gemm_mfma<<<dim3(64, 32), 256, 0, stream>>>(l1out16, outW16, out_b, logits, 2048, 4096, 512);
  softmax_rows<<<2048, 256, 0, stream>>>(logits, outp);
}

// Round 23
// 6178.245 us; speedup vs baseline: 1.2066x; 1.2066x over previous
//
#include <hip/hip_runtime.h>
#include <hip/hip_bf16.h>

// ---------------- constants ----------------
static constexpr int kT    = 2048;
static constexpr int kOUT_ELEMS = 2048 * 4096;   // output 0 size

typedef _Float16 half2_t __attribute__((ext_vector_type(2)));
typedef _Float16 half8_t __attribute__((ext_vector_type(8)));
typedef float f32x4_t __attribute__((ext_vector_type(4)));
typedef unsigned long long u64;

__device__ __forceinline__ unsigned pack_h2(float a, float b) {
  half2_t h{(_Float16)a, (_Float16)b};
  return __builtin_bit_cast(unsigned, h);
}
__device__ __forceinline__ float fdot2u(unsigned a, unsigned b, float c) {
  return __builtin_amdgcn_fdot2(__builtin_bit_cast(half2_t, a),
                                __builtin_bit_cast(half2_t, b), c, false);
}
__device__ __forceinline__ float sigm(float x) {
  return 1.f / (1.f + __expf(-x));
}
__device__ __forceinline__ float tanh_f(float x) {
  float ax = fabsf(x);
  float e = __expf(-2.f * ax);
  float r = (1.f - e) / (1.f + e);
  return x < 0.f ? -r : r;
}

// ---------------- K0: prep ----------------
// wprep6 [ld<4][p<8][e<64][j<256]: thread slot j = (row rl=j>>1, khalf q=j&1);
//   gate=rl>>5, m=rl&31, R=gate*256+32p+m, half2 col = 64q+e.
__global__ __launch_bounds__(256) void prep_kernel(
    const float* __restrict__ c_in,
    const float* __restrict__ enc_Wih, const float* __restrict__ enc_bih,
    const float* __restrict__ cenc_Wih, const float* __restrict__ cenc_bih,
    const float* __restrict__ enc_Whh, const float* __restrict__ cenc_Whh,
    const float* __restrict__ l0_Wih, const float* __restrict__ l0_Whh,
    const float* __restrict__ l1_Wih, const float* __restrict__ l1_Whh,
    const float* __restrict__ out_W,
    const float* __restrict__ l0_bih, const float* __restrict__ l0_bhh,
    const float* __restrict__ l1_bih, const float* __restrict__ l1_bhh,
    float* __restrict__ bcat,
    float* __restrict__ bias0, float* __restrict__ bias1,
    unsigned* __restrict__ wprep6, unsigned* __restrict__ wgru,
    u64* __restrict__ payz,
    _Float16* __restrict__ c16, _Float16* __restrict__ wcat16,
    _Float16* __restrict__ l0W16, _Float16* __restrict__ l1W16,
    _Float16* __restrict__ outW16) {
  int idx0 = blockIdx.x * blockDim.x + threadIdx.x;
  int stride = gridDim.x * blockDim.x;
  for (int i = idx0; i < 1024; i += stride) payz[i] = 0ull;   // re-zero every launch
  for (int i = idx0; i < 768; i += stride)
    bcat[i] = (i < 384) ? enc_bih[i] : cenc_bih[i - 384];
  for (int i = idx0; i < 2048; i += stride) {
    bias0[i] = l0_bih[i] + l0_bhh[i];
    bias1[i] = l1_bih[i] + l1_bhh[i];
  }
  for (int i = idx0; i < 4 * 8 * 64 * 256; i += stride) {
    int j = i & 255;
    int e = (i >> 8) & 63;
    int p = (i >> 14) & 7;
    int ld = i >> 17;  // layer*2 + dir
    const float* W = (ld < 2 ? l0_Whh : l1_Whh) + (ld & 1) * 1024 * 256;
    int rl = j >> 1, q = j & 1;
    int gate = rl >> 5, m = rl & 31;
    int R = gate * 256 + 32 * p + m;
    int col = 2 * (64 * q + e);
    wprep6[i] = pack_h2(W[R * 256 + col], W[R * 256 + col + 1]);
  }
  for (int i = idx0; i < 2 * 64 * 384; i += stride) {
    int row = i % 384;
    int e = (i / 384) & 63;
    int g2 = i / (64 * 384);
    const float* W = g2 ? cenc_Whh : enc_Whh;   // dir0 at base
    wgru[i] = pack_h2(W[row * 128 + 2 * e], W[row * 128 + 2 * e + 1]);
  }
  // fp16 copies for MFMA GEMMs
  for (int i = idx0; i < 2048 * 1024; i += stride) c16[i] = (_Float16)c_in[i];
  for (int i = idx0; i < 768 * 1024; i += stride) {
    int r = i >> 10, cc = i & 1023;
    float v = (r < 384) ? enc_Wih[r * 1024 + cc] : cenc_Wih[(r - 384) * 1024 + cc];
    wcat16[i] = (_Float16)v;
  }
  for (int i = idx0; i < 2048 * 1024; i += stride) l0W16[i] = (_Float16)l0_Wih[i];
  for (int i = idx0; i < 2048 * 512; i += stride)  l1W16[i] = (_Float16)l1_Wih[i];
  for (int i = idx0; i < 4096 * 512; i += stride)  outW16[i] = (_Float16)out_W[i];
}

// ---------------- MFMA GEMM body: C[M][N] = A[M][K] * B[N][K]^T + bias[N] ----------------
__device__ __forceinline__ void gemm_body(
    const _Float16* __restrict__ A, const _Float16* __restrict__ B,
    const float* __restrict__ bias, float* __restrict__ C,
    int N, int K, int bx, int by, int tid) {
  const int wave = tid >> 6, lane = tid & 63;
  const int r = lane & 15, kg = lane >> 4;
  const int m0 = by * 64 + wave * 16;
  const int n0 = bx * 64;
  const _Float16* ap = A + (size_t)(m0 + r) * K + kg * 8;
  const _Float16* bp = B + (size_t)(n0 + r) * K + kg * 8;
  f32x4_t acc0 = {0.f, 0.f, 0.f, 0.f};
  f32x4_t acc1 = {0.f, 0.f, 0.f, 0.f};
  f32x4_t acc2 = {0.f, 0.f, 0.f, 0.f};
  f32x4_t acc3 = {0.f, 0.f, 0.f, 0.f};
  for (int k0 = 0; k0 < K; k0 += 32) {
    half8_t av = *(const half8_t*)(ap + k0);
    half8_t b0 = *(const half8_t*)(bp + k0);
    half8_t b1 = *(const half8_t*)(bp + (size_t)16 * K + k0);
    half8_t b2 = *(const half8_t*)(bp + (size_t)32 * K + k0);
    half8_t b3 = *(const half8_t*)(bp + (size_t)48 * K + k0);
    acc0 = __builtin_amdgcn_mfma_f32_16x16x32_f16(av, b0, acc0, 0, 0, 0);
    acc1 = __builtin_amdgcn_mfma_f32_16x16x32_f16(av, b1, acc1, 0, 0, 0);
    acc2 = __builtin_amdgcn_mfma_f32_16x16x32_f16(av, b2, acc2, 0, 0, 0);
    acc3 = __builtin_amdgcn_mfma_f32_16x16x32_f16(av, b3, acc3, 0, 0, 0);
  }
  float bv0 = bias ? bias[n0 + r]      : 0.f;
  float bv1 = bias ? bias[n0 + 16 + r] : 0.f;
  float bv2 = bias ? bias[n0 + 32 + r] : 0.f;
  float bv3 = bias ? bias[n0 + 48 + r] : 0.f;
  const int row0 = m0 + 4 * kg;
#pragma unroll
  for (int i = 0; i < 4; ++i) {
    float* cr = C + (size_t)(row0 + i) * N + n0 + r;
    cr[0]  = acc0[i] + bv0;
    cr[16] = acc1[i] + bv1;
    cr[32] = acc2[i] + bv2;
    cr[48] = acc3[i] + bv3;
  }
}

__global__ __launch_bounds__(256) void gemm_mfma(
    const _Float16* __restrict__ A, const _Float16* __restrict__ B,
    const float* __restrict__ bias, float* __restrict__ C,
    int M, int N, int K) {
  gemm_body(A, B, bias, C, N, K, blockIdx.x, blockIdx.y, threadIdx.x);
}

// ---------------- fused: GRU chains (blocks 0..3) + cW GEMM (blocks 4..) ----------------
__global__ __launch_bounds__(384) void gru_gemm(
    const float* __restrict__ xgg,   // [T][768]
    const float* __restrict__ c_in,  // [T][1024]
    const unsigned* __restrict__ wgru,
    const float* __restrict__ enc_Wih, const float* __restrict__ enc_bih,
    const float* __restrict__ enc_bhh,
    const float* __restrict__ cenc_Wih, const float* __restrict__ cenc_bih,
    const float* __restrict__ cenc_bhh,
    float* __restrict__ u_out, float* __restrict__ cmem_out,
    const _Float16* __restrict__ c16, const _Float16* __restrict__ l0W16,
    const float* __restrict__ bias0, float* __restrict__ cW) {
  const int b = blockIdx.x, j = threadIdx.x;
  __shared__ __align__(16) unsigned h2g[64];
  __shared__ float rv[128], zv[128];
  __shared__ __align__(16) unsigned wl[384 * 26];  // 39936 B
  if (b >= 4) {
    if (j < 256) {
      int gb = b - 4;                  // 0..1023 -> 32x32 tiles
      gemm_body(c16, l0W16, bias0, cW, 2048, 1024, gb & 31, gb >> 5, j);
    }
    return;
  }
  const int gate = j >> 7, m = j & 127;
  if (b < 2) {
    const unsigned* wg = wgru + b * (64 * 384);
    const float* bhh = b ? cenc_bhh : enc_bhh;
    unsigned wv[40];
#pragma unroll
    for (int e = 0; e < 40; ++e) wv[e] = wg[e * 384 + j];
#pragma unroll
    for (int e2 = 0; e2 < 24; ++e2) wl[j * 26 + e2] = wg[(40 + e2) * 384 + j];
    const float bh = bhh[j];
    if (j < 64) h2g[j] = 0u;
    float hreg = 0.f;
    __syncthreads();
    const float* xp = xgg + b * 384 + j;
    float xc = xp[0];
    for (int t = 0; t < kT; ++t) {
      float xn = 0.f;
      if (t + 1 < kT) xn = xp[(t + 1) * 768];
      const uint4* h4 = (const uint4*)h2g;
      float a = 0.f;
#pragma unroll
      for (int k = 0; k < 10; ++k) {
        uint4 hh = h4[k];
        a = fdot2u(wv[4 * k + 0], hh.x, a);
        a = fdot2u(wv[4 * k + 1], hh.y, a);
        a = fdot2u(wv[4 * k + 2], hh.z, a);
        a = fdot2u(wv[4 * k + 3], hh.w, a);
      }
#pragma unroll
      for (int k = 0; k < 6; ++k) {
        uint4 hh = h4[10 + k];
        uint4 qw = *(const uint4*)&wl[j * 26 + 4 * k];
        a = fdot2u(qw.x, hh.x, a);
        a = fdot2u(qw.y, hh.y, a);
        a = fdot2u(qw.z, hh.z, a);
        a = fdot2u(qw.w, hh.w, a);
      }
      if (gate == 0)      rv[m] = sigm(xc + a + bh);
      else if (gate == 1) zv[m] = sigm(xc + a + bh);
      __syncthreads();
      if (gate == 2) {
        float r = rv[m], z = zv[m];
        float n = tanh_f(xc + r * (a + bh));
        hreg = (1.f - z) * n + z * hreg;
        float hx = __shfl_xor(hreg, 1);
        if (!(m & 1)) h2g[m >> 1] = pack_h2(hreg, hx);
      }
      __syncthreads();
      xc = xn;
    }
    if (gate == 2) { if (b == 0) u_out[m] = hreg; else cmem_out[m] = hreg; }
  } else {
    // backward direction: single step from zero state at t = T-1
    const float* Wih = ((b == 2) ? enc_Wih : cenc_Wih) + 384 * 1024;
    const float* bih = ((b == 2) ? enc_bih : cenc_bih) + 384;
    const float* bhh = ((b == 2) ? enc_bhh : cenc_bhh) + 384;
    const float* crow = c_in + (long)(kT - 1) * 1024;
    float a = bih[j];
    const float* wr = Wih + (long)j * 1024;
    for (int k = 0; k < 1024; k += 4) {
      float4 cv = *(const float4*)&crow[k];
      float4 wv4 = *(const float4*)&wr[k];
      a += cv.x * wv4.x + cv.y * wv4.y + cv.z * wv4.z + cv.w * wv4.w;
    }
    const float bh = bhh[j];
    if (gate == 0)      rv[m] = sigm(a + bh);
    else if (gate == 1) zv[m] = sigm(a + bh);
    __syncthreads();
    if (gate == 2) {
      float r = rv[m], z = zv[m];
      float n = tanh_f(a + r * bh);
      float h = (1.f - z) * n;
      if (b == 2) u_out[128 + m] = h; else cmem_out[128 + m] = h;
    }
  }
}

// ---------------- attention ----------------
__global__ __launch_bounds__(256) void attn_dots(
    const float* __restrict__ mem, const float* __restrict__ u, float* __restrict__ d) {
  __shared__ float us[256];
  int tid = threadIdx.x;
  us[tid] = u[tid];
  __syncthreads();
  int g = tid >> 3, l8 = tid & 7;
  int row = blockIdx.x * 32 + g;
  const float* mr = mem + (long)row * 256 + l8 * 32;
  float p = 0.f;
#pragma unroll
  for (int k = 0; k < 32; k += 4) {
    float4 m4 = *(const float4*)&mr[k];
    p += m4.x * us[l8 * 32 + k] + m4.y * us[l8 * 32 + k + 1] +
         m4.z * us[l8 * 32 + k + 2] + m4.w * us[l8 * 32 + k + 3];
  }
  p += __shfl_down(p, 4);
  p += __shfl_down(p, 2);
  p += __shfl_down(p, 1);
  if (l8 == 0) d[row] = p;
}

__global__ __launch_bounds__(1024) void attn_soft(
    const float* __restrict__ d, float* __restrict__ p, float* __restrict__ h_acc) {
  __shared__ float red[1024];
  int tid = threadIdx.x;
  float v[8];
  float mx = -1e30f;
#pragma unroll
  for (int i = 0; i < 8; i++) { v[i] = d[tid * 8 + i]; mx = fmaxf(mx, v[i]); }
  red[tid] = mx; __syncthreads();
  for (int s = 512; s > 0; s >>= 1) {
    if (tid < s) red[tid] = fmaxf(red[tid], red[tid + s]);
    __syncthreads();
  }
  mx = red[0]; __syncthreads();
  float sm = 0.f; float e[8];
#pragma unroll
  for (int i = 0; i < 8; i++) { e[i] = __expf(v[i] - mx); sm += e[i]; }
  red[tid] = sm; __syncthreads();
  for (int s = 512; s > 0; s >>= 1) {
    if (tid < s) red[tid] += red[tid + s];
    __syncthreads();
  }
  float rz = 1.f / red[0];
#pragma unroll
  for (int i = 0; i < 8; i++) p[tid * 8 + i] = e[i] * rz;
  if (tid < 256) h_acc[tid] = 0.f;
}

__global__ __launch_bounds__(256) void attn_h(
    const float* __restrict__ mem, const float* __restrict__ p, float* __restrict__ h_acc) {
  int tid = threadIdx.x;
  int r0 = blockIdx.x * 128;
  float acc = 0.f;
  for (int i = 0; i < 128; i++) acc += p[r0 + i] * mem[(long)(r0 + i) * 256 + tid];
  atomicAdd(&h_acc[tid], acc);
}

__global__ __launch_bounds__(128) void attn_o(
    const float* __restrict__ u, const float* __restrict__ h_acc,
    const float* __restrict__ know_W, const float* __restrict__ know_b,
    float* __restrict__ o) {
  __shared__ float uh[256];
  int tid = threadIdx.x;
  uh[tid] = u[tid] + h_acc[tid];
  uh[128 + tid] = u[128 + tid] + h_acc[128 + tid];
  __syncthreads();
  int row = blockIdx.x * 128 + tid;
  float acc = know_b[row];
  for (int k = 0; k < 256; k += 4) {
    float4 w4 = *(const float4*)&know_W[row * 256 + k];
    acc += w4.x * uh[k] + w4.y * uh[k + 1] + w4.z * uh[k + 2] + w4.w * uh[k + 3];
  }
  o[row] = acc;
}

__global__ __launch_bounds__(128) void attn_ov(
    const float* __restrict__ o, const float* __restrict__ Wih0, float* __restrict__ ov) {
  int row = blockIdx.x * 128 + threadIdx.x;
  float acc = 0.f;
  for (int k = 0; k < 1024; k += 4) {
    float4 w4 = *(const float4*)&Wih0[(long)row * 1024 + k];
    float4 o4 = *(const float4*)&o[k];
    acc += w4.x * o4.x + w4.y * o4.y + w4.z * o4.z + w4.w * o4.w;
  }
  ov[row] = acc;
}

// ---------------- LSTM v23: 8 CUs/direction, (row, K-half) threads ----------------
// grid = 64; active: bid&7 in {0,1}; dir = bid&7, p = bid>>3 (0..7); all 8 p-blocks of
// a direction on one XCD (bid%8 round-robin). Block owns h-elems [32p,32p+32) =
// 128 gate rows. Thread j: row rl=j>>1, K-half q=j&1: 64 half2 weights =
// 48 VGPR (demand ~75 <= 84 grant; small arrays are held) + 16 LDS (stride-20,
// 16B aligned). Partials combined via shfl_xor(1). 7-peer tagged-u64 exchange
// (112 polling lanes x 16 u64); skew<=1 by full bipartite dependence.
__global__ __launch_bounds__(256) void lstm_cc8(
    const unsigned* __restrict__ wp6,    // layer base: [dir<2][p<8][e<64][j<256]
    const float* __restrict__ xg,        // [T][2048] (biases folded)
    const float* __restrict__ extra,     // [2048] rank-1 add or nullptr
    _Float16* __restrict__ out16,        // [T][512] fp16
    u64* __restrict__ pay) {             // layer base: [dir*8+p][slot<2][16] u64
  const int bid = blockIdx.x;
  const int xs = bid & 7;
  if (xs >= 2) return;
  const int dir = xs, p = bid >> 3;      // p in [0,8)
  const int j = threadIdx.x;             // [0,256)
  const int rl = j >> 1, q = j & 1;
  const int gate = rl >> 5;
  const int m = rl & 31;
  const int R = gate * 256 + 32 * p + m; // global gate row

  __shared__ __align__(16) unsigned wl[256 * 20];  // 20480 B
  __shared__ __align__(16) unsigned h2v[128];
  __shared__ float gact[128];

  const unsigned* base = wp6 + (size_t)dir * 131072 + (size_t)p * 16384;
  unsigned wv[48];
#pragma unroll
  for (int e = 0; e < 48; ++e) wv[e] = base[e * 256 + j];
#pragma unroll
  for (int e2 = 0; e2 < 16; ++e2) wl[j * 20 + e2] = base[(48 + e2) * 256 + j];

  float exv = extra ? extra[dir * 1024 + R] : 0.f;
  if (j < 128) h2v[j] = 0u;
  float cst = 0.f;
  __syncthreads();

  u64* mypay = pay + (dir * 8 + p) * 32;
  // polling lanes j<112: pi = j>>4 (0..6), peer p' = pi + (pi>=p)
  const int pi = (j < 112) ? (j >> 4) : 0;
  const int pp = pi + (pi >= p ? 1 : 0);
  u64* peerpay = pay + (dir * 8 + pp) * 32;
  const int pidx = j & 15;

  const float* xp = xg + dir * 1024;
  const int t0 = dir ? (kT - 1) : 0;
  const int dt = dir ? -1 : 1;
  float xc = xp[(long)t0 * 2048 + R] + exv;

  for (int s = 0; s < kT; ++s) {
    const int t = t0 + s * dt;
    float xn_ = 0.f;
    if (s + 1 < kT) xn_ = xp[(long)(t + dt) * 2048 + R];
    // consume 7 peers' h-slices for step s
    if (j < 112 && s > 0) {
      u64 v;
      int guard = 0;
      do {
        v = __hip_atomic_load(&peerpay[(s & 1) * 16 + pidx],
                              __ATOMIC_RELAXED, __HIP_MEMORY_SCOPE_AGENT);
      } while ((unsigned)(v >> 32) < (unsigned)s && ++guard < (1 << 18));
      h2v[16 * pp + pidx] = (unsigned)v;
    }
    __syncthreads();
    // K-half dot: h2 chunks [16q, 16q+16)
    const uint4* h4 = ((const uint4*)h2v) + 16 * q;
    float acc = 0.f;
#pragma unroll
    for (int c = 0; c < 12; ++c) {
      uint4 hh = h4[c];
      acc = fdot2u(wv[4 * c + 0], hh.x, acc);
      acc = fdot2u(wv[4 * c + 1], hh.y, acc);
      acc = fdot2u(wv[4 * c + 2], hh.z, acc);
      acc = fdot2u(wv[4 * c + 3], hh.w, acc);
    }
#pragma unroll
    for (int c = 0; c < 4; ++c) {
      uint4 hh = h4[12 + c];
      uint4 qw = *(const uint4*)&wl[j * 20 + 4 * c];
      acc = fdot2u(qw.x, hh.x, acc);
      acc = fdot2u(qw.y, hh.y, acc);
      acc = fdot2u(qw.z, hh.z, acc);
      acc = fdot2u(qw.w, hh.w, acc);
    }
    acc += __shfl_xor(acc, 1);       // combine K-halves (adjacent lanes, same row)
    float sv = acc + xc;
    float act = (gate == 2) ? tanh_f(sv) : sigm(sv);
    if (!q) gact[rl] = act;
    __syncthreads();
    if (j < 32) {
      float iv  = gact[j];
      float fv  = gact[32 + j];
      float gv  = gact[64 + j];
      float ovv = gact[96 + j];
      cst = fv * cst + iv * gv;
      float h = ovv * tanh_f(cst);
      out16[(long)t * 512 + dir * 256 + 32 * p + j] = (_Float16)h;
      float hx = __shfl_xor(h, 1);
      if (!(j & 1)) {
        int idx = j >> 1;                       // 0..15
        unsigned hp = pack_h2(h, hx);
        h2v[16 * p + idx] = hp;                 // own slice for next step
        u64 tagged = ((u64)(unsigned)(s + 1) << 32) | (u64)hp;
        __hip_atomic_store(&mypay[((s + 1) & 1) * 16 + idx], tagged,
                           __ATOMIC_RELAXED, __HIP_MEMORY_SCOPE_AGENT);
      }
    }
    xc = xn_ + exv;
  }
}

// ---------------- final row softmax ----------------
__global__ __launch_bounds__(256) void softmax_rows(
    const float* __restrict__ logits, float* __restrict__ outp) {
  int t = blockIdx.x, tid = threadIdx.x;
  __shared__ float red[256];
  const float* lr = logits + (long)t * 4096;
  float v[16];
  float mx = -1e30f;
#pragma unroll
  for (int i = 0; i < 16; i++) { v[i] = lr[tid + 256 * i]; mx = fmaxf(mx, v[i]); }
  red[tid] = mx; __syncthreads();
  for (int s = 128; s > 0; s >>= 1) {
    if (tid < s) red[tid] = fmaxf(red[tid], red[tid + s]);
    __syncthreads();
  }
  mx = red[0]; __syncthreads();
  float sm = 0.f;
#pragma unroll
  for (int i = 0; i < 16; i++) { v[i] = __expf(v[i] - mx); sm += v[i]; }
  red[tid] = sm; __syncthreads();
  for (int s = 128; s > 0; s >>= 1) {
    if (tid < s) red[tid] += red[tid + s];
    __syncthreads();
  }
  float rz = 1.f / red[0];
#pragma unroll
  for (int i = 0; i < 16; i++) outp[(long)t * 4096 + tid + 256 * i] = v[i] * rz;
}

// ---------------- launch ----------------
extern "C" void kernel_launch(void* const* d_in, const int* in_sizes, int n_in,
                              void* d_out, int out_size, void* d_ws, size_t ws_size,
                              hipStream_t stream) {
  const float* c        = (const float*)d_in[0];
  const float* memory   = (const float*)d_in[1];
  const float* enc_Wih  = (const float*)d_in[2];
  const float* enc_Whh  = (const float*)d_in[3];
  const float* enc_bih  = (const float*)d_in[4];
  const float* enc_bhh  = (const float*)d_in[5];
  const float* cenc_Wih = (const float*)d_in[6];
  const float* cenc_Whh = (const float*)d_in[7];
  const float* cenc_bih = (const float*)d_in[8];
  const float* cenc_bhh = (const float*)d_in[9];
  const float* know_W   = (const float*)d_in[10];
  const float* know_b   = (const float*)d_in[11];
  const float* l0_Wih   = (const float*)d_in[12];
  const float* l0_Whh   = (const float*)d_in[13];
  const float* l0_bih   = (const float*)d_in[14];
  const float* l0_bhh   = (const float*)d_in[15];
  const float* l1_Wih   = (const float*)d_in[16];
  const float* l1_Whh   = (const float*)d_in[17];
  const float* l1_bih   = (const float*)d_in[18];
  const float* l1_bhh   = (const float*)d_in[19];
  const float* out_W    = (const float*)d_in[20];
  const float* out_b    = (const float*)d_in[21];

  float* ws = (float*)d_ws;
  float* outp = (float*)d_out;

  float* xgg   = ws;                  // 1,572,864   [T][768]
  float* cW    = ws + 1572864;        // 4,194,304   [T][2048] (ends 5,767,168)
  _Float16* l0out16 = (_Float16*)(ws + 5767168);  // 524,288 floats; dead before gemm4
  float* xg1   = ws + 7602176;        // 4,194,304   [T][2048]
  unsigned* wprep6 = (unsigned*)(ws + 11796480);  // 524,288 u32
  float* bcat  = ws + 12320768;       // 768
  float* bias0 = ws + 12321536;       // 2048
  float* bias1 = ws + 12323584;       // 2048
  float* u_vec = ws + 12325632;       // 256
  float* d_att = ws + 12325888;       // 8192
  float* p_att = ws + 12334080;       // 8192
  float* h_acc = ws + 12342272;       // 256
  float* o_vec = ws + 12342528;       // 1024
  float* ov    = ws + 12343552;       // 2048
  unsigned* wgru = (unsigned*)(ws + 13656320);      // 49,152 u32
  u64* payload = (u64*)(ws + 13705472);             // 1024 u64 (ends 13,707,520)
  float* logits = ws;                 // 8,388,608   aliases [0, 8.39M): all dead by gemm4

  _Float16* c16     = (_Float16*)(ws + 12345600);  // 1,048,576 floats; dead after gru_gemm
  _Float16* l1out16 = (_Float16*)(ws + 12345600);  // reuses c16 space; outside logits
  _Float16* wcat16  = (_Float16*)(ws + 7602176);   // in xg1: dead until gemm3 writes xg1
  _Float16* l0W16   = (_Float16*)(ws + 7995392);   // in xg1: used in gru_gemm < gemm3
  _Float16* l1W16   = (_Float16*)(ws + 13707520);  // 524,288 floats
  _Float16* outW16  = (_Float16*)(ws + 14231808);  // 1,048,576 floats (end 15,280,384)

  prep_kernel<<<512, 256, 0, stream>>>(c, enc_Wih, enc_bih, cenc_Wih, cenc_bih,
                                       enc_Whh, cenc_Whh,
                                       l0_Wih, l0_Whh, l1_Wih, l1_Whh, out_W,
                                       l0_bih, l0_bhh, l1_bih, l1_bhh,
                                       bcat, bias0, bias1, wprep6, wgru, payload,
                                       c16, wcat16, l0W16, l1W16, outW16);
  gemm_mfma<<<dim3(12, 32), 256, 0, stream>>>(c16, wcat16, bcat, xgg, 2048, 768, 1024);
  gru_gemm<<<1028, 384, 0, stream>>>(xgg, c, wgru, enc_Wih, enc_bih, enc_bhh,
                                     cenc_Wih, cenc_bih, cenc_bhh,
                                     u_vec, outp + kOUT_ELEMS,
                                     c16, l0W16, bias0, cW);
  attn_dots<<<256, 256, 0, stream>>>(memory, u_vec, d_att);
  attn_soft<<<1, 1024, 0, stream>>>(d_att, p_att, h_acc);
  attn_h<<<64, 256, 0, stream>>>(memory, p_att, h_acc);
  attn_o<<<8, 128, 0, stream>>>(u_vec, h_acc, know_W, know_b, o_vec);
  attn_ov<<<16, 128, 0, stream>>>(o_vec, l0_Wih, ov);
  lstm_cc8<<<64, 256, 0, stream>>>(wprep6, cW, ov, l0out16, payload);
  gemm_mfma<<<dim3(32, 32), 256, 0, stream>>>(l0out16, l1W16, bias1, xg1, 2048, 2048, 512);
  lstm_cc8<<<64, 256, 0, stream>>>(wprep6 + 262144, xg1, nullptr, l1out16, payload + 512);
  gemm_mfma<<<dim3(64, 32), 256, 0, stream>>>(l1out16, outW16, out_b, logits, 2048, 4096, 512);
  softmax_rows<<<2048, 256, 0, stream>>>(logits, outp);
}

// Round 24
// 5849.365 us; speedup vs baseline: 1.2744x; 1.0562x over previous
//
#include <hip/hip_runtime.h>
#include <hip/hip_bf16.h>

// ---------------- constants ----------------
static constexpr int kT    = 2048;
static constexpr int kOUT_ELEMS = 2048 * 4096;   // output 0 size

typedef _Float16 half2_t __attribute__((ext_vector_type(2)));
typedef _Float16 half8_t __attribute__((ext_vector_type(8)));
typedef float f32x4_t __attribute__((ext_vector_type(4)));
typedef unsigned long long u64;

__device__ __forceinline__ unsigned pack_h2(float a, float b) {
  half2_t h{(_Float16)a, (_Float16)b};
  return __builtin_bit_cast(unsigned, h);
}
__device__ __forceinline__ float fdot2u(unsigned a, unsigned b, float c) {
  return __builtin_amdgcn_fdot2(__builtin_bit_cast(half2_t, a),
                                __builtin_bit_cast(half2_t, b), c, false);
}
__device__ __forceinline__ float sigm(float x) {
  return 1.f / (1.f + __expf(-x));
}
__device__ __forceinline__ float tanh_f(float x) {
  float ax = fabsf(x);
  float e = __expf(-2.f * ax);
  float r = (1.f - e) / (1.f + e);
  return x < 0.f ? -r : r;
}

// ---------------- K0: prep ----------------
// wprep7 [ld<4][p<16][e<32][j<256]: thread slot j = (row rl=j>>2, kquarter qk=j&3);
//   gate=rl>>4, m=rl&15, R=gate*256+16p+m, half2 col = 32qk+e.
__global__ __launch_bounds__(256) void prep_kernel(
    const float* __restrict__ c_in,
    const float* __restrict__ enc_Wih, const float* __restrict__ enc_bih,
    const float* __restrict__ cenc_Wih, const float* __restrict__ cenc_bih,
    const float* __restrict__ enc_Whh, const float* __restrict__ cenc_Whh,
    const float* __restrict__ l0_Wih, const float* __restrict__ l0_Whh,
    const float* __restrict__ l1_Wih, const float* __restrict__ l1_Whh,
    const float* __restrict__ out_W,
    const float* __restrict__ l0_bih, const float* __restrict__ l0_bhh,
    const float* __restrict__ l1_bih, const float* __restrict__ l1_bhh,
    float* __restrict__ bcat,
    float* __restrict__ bias0, float* __restrict__ bias1,
    unsigned* __restrict__ wprep7, unsigned* __restrict__ wgru,
    u64* __restrict__ payz,
    _Float16* __restrict__ c16, _Float16* __restrict__ wcat16,
    _Float16* __restrict__ l0W16, _Float16* __restrict__ l1W16,
    _Float16* __restrict__ outW16) {
  int idx0 = blockIdx.x * blockDim.x + threadIdx.x;
  int stride = gridDim.x * blockDim.x;
  for (int i = idx0; i < 1024; i += stride) payz[i] = 0ull;   // re-zero every launch
  for (int i = idx0; i < 768; i += stride)
    bcat[i] = (i < 384) ? enc_bih[i] : cenc_bih[i - 384];
  for (int i = idx0; i < 2048; i += stride) {
    bias0[i] = l0_bih[i] + l0_bhh[i];
    bias1[i] = l1_bih[i] + l1_bhh[i];
  }
  for (int i = idx0; i < 4 * 16 * 32 * 256; i += stride) {
    int j = i & 255;
    int e = (i >> 8) & 31;
    int p = (i >> 13) & 15;
    int ld = i >> 17;  // layer*2 + dir
    const float* W = (ld < 2 ? l0_Whh : l1_Whh) + (ld & 1) * 1024 * 256;
    int rl = j >> 2, qk = j & 3;
    int gate = rl >> 4, m = rl & 15;
    int R = gate * 256 + 16 * p + m;
    int col = 2 * (32 * qk + e);
    wprep7[i] = pack_h2(W[R * 256 + col], W[R * 256 + col + 1]);
  }
  for (int i = idx0; i < 2 * 64 * 384; i += stride) {
    int row = i % 384;
    int e = (i / 384) & 63;
    int g2 = i / (64 * 384);
    const float* W = g2 ? cenc_Whh : enc_Whh;   // dir0 at base
    wgru[i] = pack_h2(W[row * 128 + 2 * e], W[row * 128 + 2 * e + 1]);
  }
  // fp16 copies for MFMA GEMMs
  for (int i = idx0; i < 2048 * 1024; i += stride) c16[i] = (_Float16)c_in[i];
  for (int i = idx0; i < 768 * 1024; i += stride) {
    int r = i >> 10, cc = i & 1023;
    float v = (r < 384) ? enc_Wih[r * 1024 + cc] : cenc_Wih[(r - 384) * 1024 + cc];
    wcat16[i] = (_Float16)v;
  }
  for (int i = idx0; i < 2048 * 1024; i += stride) l0W16[i] = (_Float16)l0_Wih[i];
  for (int i = idx0; i < 2048 * 512; i += stride)  l1W16[i] = (_Float16)l1_Wih[i];
  for (int i = idx0; i < 4096 * 512; i += stride)  outW16[i] = (_Float16)out_W[i];
}

// ---------------- MFMA GEMM body: C[M][N] = A[M][K] * B[N][K]^T + bias[N] ----------------
__device__ __forceinline__ void gemm_body(
    const _Float16* __restrict__ A, const _Float16* __restrict__ B,
    const float* __restrict__ bias, float* __restrict__ C,
    int N, int K, int bx, int by, int tid) {
  const int wave = tid >> 6, lane = tid & 63;
  const int r = lane & 15, kg = lane >> 4;
  const int m0 = by * 64 + wave * 16;
  const int n0 = bx * 64;
  const _Float16* ap = A + (size_t)(m0 + r) * K + kg * 8;
  const _Float16* bp = B + (size_t)(n0 + r) * K + kg * 8;
  f32x4_t acc0 = {0.f, 0.f, 0.f, 0.f};
  f32x4_t acc1 = {0.f, 0.f, 0.f, 0.f};
  f32x4_t acc2 = {0.f, 0.f, 0.f, 0.f};
  f32x4_t acc3 = {0.f, 0.f, 0.f, 0.f};
  for (int k0 = 0; k0 < K; k0 += 32) {
    half8_t av = *(const half8_t*)(ap + k0);
    half8_t b0 = *(const half8_t*)(bp + k0);
    half8_t b1 = *(const half8_t*)(bp + (size_t)16 * K + k0);
    half8_t b2 = *(const half8_t*)(bp + (size_t)32 * K + k0);
    half8_t b3 = *(const half8_t*)(bp + (size_t)48 * K + k0);
    acc0 = __builtin_amdgcn_mfma_f32_16x16x32_f16(av, b0, acc0, 0, 0, 0);
    acc1 = __builtin_amdgcn_mfma_f32_16x16x32_f16(av, b1, acc1, 0, 0, 0);
    acc2 = __builtin_amdgcn_mfma_f32_16x16x32_f16(av, b2, acc2, 0, 0, 0);
    acc3 = __builtin_amdgcn_mfma_f32_16x16x32_f16(av, b3, acc3, 0, 0, 0);
  }
  float bv0 = bias ? bias[n0 + r]      : 0.f;
  float bv1 = bias ? bias[n0 + 16 + r] : 0.f;
  float bv2 = bias ? bias[n0 + 32 + r] : 0.f;
  float bv3 = bias ? bias[n0 + 48 + r] : 0.f;
  const int row0 = m0 + 4 * kg;
#pragma unroll
  for (int i = 0; i < 4; ++i) {
    float* cr = C + (size_t)(row0 + i) * N + n0 + r;
    cr[0]  = acc0[i] + bv0;
    cr[16] = acc1[i] + bv1;
    cr[32] = acc2[i] + bv2;
    cr[48] = acc3[i] + bv3;
  }
}

__global__ __launch_bounds__(256) void gemm_mfma(
    const _Float16* __restrict__ A, const _Float16* __restrict__ B,
    const float* __restrict__ bias, float* __restrict__ C,
    int M, int N, int K) {
  gemm_body(A, B, bias, C, N, K, blockIdx.x, blockIdx.y, threadIdx.x);
}

// ---------------- fused: GRU chains (blocks 0..3) + cW GEMM (blocks 4..) ----------------
__global__ __launch_bounds__(384) void gru_gemm(
    const float* __restrict__ xgg,   // [T][768]
    const float* __restrict__ c_in,  // [T][1024]
    const unsigned* __restrict__ wgru,
    const float* __restrict__ enc_Wih, const float* __restrict__ enc_bih,
    const float* __restrict__ enc_bhh,
    const float* __restrict__ cenc_Wih, const float* __restrict__ cenc_bih,
    const float* __restrict__ cenc_bhh,
    float* __restrict__ u_out, float* __restrict__ cmem_out,
    const _Float16* __restrict__ c16, const _Float16* __restrict__ l0W16,
    const float* __restrict__ bias0, float* __restrict__ cW) {
  const int b = blockIdx.x, j = threadIdx.x;
  __shared__ __align__(16) unsigned h2g[64];
  __shared__ float rv[128], zv[128];
  __shared__ __align__(16) unsigned wl[384 * 26];  // 39936 B
  if (b >= 4) {
    if (j < 256) {
      int gb = b - 4;                  // 0..1023 -> 32x32 tiles
      gemm_body(c16, l0W16, bias0, cW, 2048, 1024, gb & 31, gb >> 5, j);
    }
    return;
  }
  const int gate = j >> 7, m = j & 127;
  if (b < 2) {
    const unsigned* wg = wgru + b * (64 * 384);
    const float* bhh = b ? cenc_bhh : enc_bhh;
    unsigned wv[40];
#pragma unroll
    for (int e = 0; e < 40; ++e) wv[e] = wg[e * 384 + j];
#pragma unroll
    for (int e2 = 0; e2 < 24; ++e2) wl[j * 26 + e2] = wg[(40 + e2) * 384 + j];
    const float bh = bhh[j];
    if (j < 64) h2g[j] = 0u;
    float hreg = 0.f;
    __syncthreads();
    const float* xp = xgg + b * 384 + j;
    float xc = xp[0];
    for (int t = 0; t < kT; ++t) {
      float xn = 0.f;
      if (t + 1 < kT) xn = xp[(t + 1) * 768];
      const uint4* h4 = (const uint4*)h2g;
      float a = 0.f;
#pragma unroll
      for (int k = 0; k < 10; ++k) {
        uint4 hh = h4[k];
        a = fdot2u(wv[4 * k + 0], hh.x, a);
        a = fdot2u(wv[4 * k + 1], hh.y, a);
        a = fdot2u(wv[4 * k + 2], hh.z, a);
        a = fdot2u(wv[4 * k + 3], hh.w, a);
      }
#pragma unroll
      for (int k = 0; k < 6; ++k) {
        uint4 hh = h4[10 + k];
        uint4 qw = *(const uint4*)&wl[j * 26 + 4 * k];
        a = fdot2u(qw.x, hh.x, a);
        a = fdot2u(qw.y, hh.y, a);
        a = fdot2u(qw.z, hh.z, a);
        a = fdot2u(qw.w, hh.w, a);
      }
      if (gate == 0)      rv[m] = sigm(xc + a + bh);
      else if (gate == 1) zv[m] = sigm(xc + a + bh);
      __syncthreads();
      if (gate == 2) {
        float r = rv[m], z = zv[m];
        float n = tanh_f(xc + r * (a + bh));
        hreg = (1.f - z) * n + z * hreg;
        float hx = __shfl_xor(hreg, 1);
        if (!(m & 1)) h2g[m >> 1] = pack_h2(hreg, hx);
      }
      __syncthreads();
      xc = xn;
    }
    if (gate == 2) { if (b == 0) u_out[m] = hreg; else cmem_out[m] = hreg; }
  } else {
    // backward direction: single step from zero state at t = T-1
    const float* Wih = ((b == 2) ? enc_Wih : cenc_Wih) + 384 * 1024;
    const float* bih = ((b == 2) ? enc_bih : cenc_bih) + 384;
    const float* bhh = ((b == 2) ? enc_bhh : cenc_bhh) + 384;
    const float* crow = c_in + (long)(kT - 1) * 1024;
    float a = bih[j];
    const float* wr = Wih + (long)j * 1024;
    for (int k = 0; k < 1024; k += 4) {
      float4 cv = *(const float4*)&crow[k];
      float4 wv4 = *(const float4*)&wr[k];
      a += cv.x * wv4.x + cv.y * wv4.y + cv.z * wv4.z + cv.w * wv4.w;
    }
    const float bh = bhh[j];
    if (gate == 0)      rv[m] = sigm(a + bh);
    else if (gate == 1) zv[m] = sigm(a + bh);
    __syncthreads();
    if (gate == 2) {
      float r = rv[m], z = zv[m];
      float n = tanh_f(a + r * bh);
      float h = (1.f - z) * n;
      if (b == 2) u_out[128 + m] = h; else cmem_out[128 + m] = h;
    }
  }
}

// ---------------- attention ----------------
__global__ __launch_bounds__(256) void attn_dots(
    const float* __restrict__ mem, const float* __restrict__ u, float* __restrict__ d) {
  __shared__ float us[256];
  int tid = threadIdx.x;
  us[tid] = u[tid];
  __syncthreads();
  int g = tid >> 3, l8 = tid & 7;
  int row = blockIdx.x * 32 + g;
  const float* mr = mem + (long)row * 256 + l8 * 32;
  float p = 0.f;
#pragma unroll
  for (int k = 0; k < 32; k += 4) {
    float4 m4 = *(const float4*)&mr[k];
    p += m4.x * us[l8 * 32 + k] + m4.y * us[l8 * 32 + k + 1] +
         m4.z * us[l8 * 32 + k + 2] + m4.w * us[l8 * 32 + k + 3];
  }
  p += __shfl_down(p, 4);
  p += __shfl_down(p, 2);
  p += __shfl_down(p, 1);
  if (l8 == 0) d[row] = p;
}

__global__ __launch_bounds__(1024) void attn_soft(
    const float* __restrict__ d, float* __restrict__ p, float* __restrict__ h_acc) {
  __shared__ float red[1024];
  int tid = threadIdx.x;
  float v[8];
  float mx = -1e30f;
#pragma unroll
  for (int i = 0; i < 8; i++) { v[i] = d[tid * 8 + i]; mx = fmaxf(mx, v[i]); }
  red[tid] = mx; __syncthreads();
  for (int s = 512; s > 0; s >>= 1) {
    if (tid < s) red[tid] = fmaxf(red[tid], red[tid + s]);
    __syncthreads();
  }
  mx = red[0]; __syncthreads();
  float sm = 0.f; float e[8];
#pragma unroll
  for (int i = 0; i < 8; i++) { e[i] = __expf(v[i] - mx); sm += e[i]; }
  red[tid] = sm; __syncthreads();
  for (int s = 512; s > 0; s >>= 1) {
    if (tid < s) red[tid] += red[tid + s];
    __syncthreads();
  }
  float rz = 1.f / red[0];
#pragma unroll
  for (int i = 0; i < 8; i++) p[tid * 8 + i] = e[i] * rz;
  if (tid < 256) h_acc[tid] = 0.f;
}

__global__ __launch_bounds__(256) void attn_h(
    const float* __restrict__ mem, const float* __restrict__ p, float* __restrict__ h_acc) {
  int tid = threadIdx.x;
  int r0 = blockIdx.x * 128;
  float acc = 0.f;
  for (int i = 0; i < 128; i++) acc += p[r0 + i] * mem[(long)(r0 + i) * 256 + tid];
  atomicAdd(&h_acc[tid], acc);
}

__global__ __launch_bounds__(128) void attn_o(
    const float* __restrict__ u, const float* __restrict__ h_acc,
    const float* __restrict__ know_W, const float* __restrict__ know_b,
    float* __restrict__ o) {
  __shared__ float uh[256];
  int tid = threadIdx.x;
  uh[tid] = u[tid] + h_acc[tid];
  uh[128 + tid] = u[128 + tid] + h_acc[128 + tid];
  __syncthreads();
  int row = blockIdx.x * 128 + tid;
  float acc = know_b[row];
  for (int k = 0; k < 256; k += 4) {
    float4 w4 = *(const float4*)&know_W[row * 256 + k];
    acc += w4.x * uh[k] + w4.y * uh[k + 1] + w4.z * uh[k + 2] + w4.w * uh[k + 3];
  }
  o[row] = acc;
}

__global__ __launch_bounds__(128) void attn_ov(
    const float* __restrict__ o, const float* __restrict__ Wih0, float* __restrict__ ov) {
  int row = blockIdx.x * 128 + threadIdx.x;
  float acc = 0.f;
  for (int k = 0; k < 1024; k += 4) {
    float4 w4 = *(const float4*)&Wih0[(long)row * 1024 + k];
    float4 o4 = *(const float4*)&o[k];
    acc += w4.x * o4.x + w4.y * o4.y + w4.z * o4.z + w4.w * o4.w;
  }
  ov[row] = acc;
}

// ---------------- LSTM v24: 16 CUs/direction, (row, K-quarter) threads ----------------
// grid = 128; active: bid&7 in {0,1}; dir = bid&7, p = bid>>3 (0..15); all 16
// p-blocks of a direction land on one XCD (bid%8 round-robin). Block owns h-elems
// [16p,16p+16) = 64 gate rows. Thread j: row rl=j>>2, K-quarter qk=j&3:
// 32 half2 weights ALL in VGPR (no LDS slab, no staging). Quarter partials via
// shfl_xor(1)+shfl_xor(2) within the 4-lane quad. 15-peer tagged-u64 exchange:
// 120 polling lanes x 1 u64 (single parallel RTT). Skew<=1 by bipartite dependence.
__global__ __launch_bounds__(256) void lstm_cc16(
    const unsigned* __restrict__ wp7,    // layer base: [dir<2][p<16][e<32][j<256]
    const float* __restrict__ xg,        // [T][2048] (biases folded)
    const float* __restrict__ extra,     // [2048] rank-1 add or nullptr
    _Float16* __restrict__ out16,        // [T][512] fp16
    u64* __restrict__ pay) {             // layer base: [dir*16+p][slot<2][8] u64
  const int bid = blockIdx.x;
  const int xs = bid & 7;
  if (xs >= 2) return;
  const int dir = xs, p = bid >> 3;      // p in [0,16)
  const int j = threadIdx.x;             // [0,256)
  const int rl = j >> 2, qk = j & 3;
  const int gate = rl >> 4;
  const int m = rl & 15;
  const int R = gate * 256 + 16 * p + m; // global gate row

  __shared__ __align__(16) unsigned h2v[128];
  __shared__ float gact[64];

  const unsigned* base = wp7 + (size_t)dir * 131072 + (size_t)p * 8192;
  unsigned wv[32];
#pragma unroll
  for (int e = 0; e < 32; ++e) wv[e] = base[e * 256 + j];

  float exv = extra ? extra[dir * 1024 + R] : 0.f;
  if (j < 128) h2v[j] = 0u;
  float cst = 0.f;
  __syncthreads();

  u64* mypay = pay + (dir * 16 + p) * 16;
  // polling lanes j<120: pi = j>>3 (0..14), peer p' = pi + (pi>=p)
  const int pi = (j < 120) ? (j >> 3) : 0;
  const int pp = pi + (pi >= p ? 1 : 0);
  u64* peerpay = pay + (dir * 16 + pp) * 16;
  const int pidx = j & 7;

  const float* xp = xg + dir * 1024;
  const int t0 = dir ? (kT - 1) : 0;
  const int dt = dir ? -1 : 1;
  float xc = xp[(long)t0 * 2048 + R] + exv;

  for (int s = 0; s < kT; ++s) {
    const int t = t0 + s * dt;
    float xn_ = 0.f;
    if (s + 1 < kT) xn_ = xp[(long)(t + dt) * 2048 + R];
    // consume 15 peers' h-slices for step s (tag >= s), per-lane single-u64 spin
    if (j < 120 && s > 0) {
      u64 v;
      int guard = 0;
      do {
        v = __hip_atomic_load(&peerpay[(s & 1) * 8 + pidx],
                              __ATOMIC_RELAXED, __HIP_MEMORY_SCOPE_AGENT);
      } while ((unsigned)(v >> 32) < (unsigned)s && ++guard < (1 << 18));
      h2v[8 * pp + pidx] = (unsigned)v;
    }
    __syncthreads();
    // K-quarter dot: h2 chunks [8qk, 8qk+8)
    const uint4* h4 = ((const uint4*)h2v) + 8 * qk;
    float acc = 0.f;
#pragma unroll
    for (int c = 0; c < 8; ++c) {
      uint4 hh = h4[c];
      acc = fdot2u(wv[4 * c + 0], hh.x, acc);
      acc = fdot2u(wv[4 * c + 1], hh.y, acc);
      acc = fdot2u(wv[4 * c + 2], hh.z, acc);
      acc = fdot2u(wv[4 * c + 3], hh.w, acc);
    }
    acc += __shfl_xor(acc, 1);       // combine K-quarters within the lane quad
    acc += __shfl_xor(acc, 2);
    float sv = acc + xc;
    float act = (gate == 2) ? tanh_f(sv) : sigm(sv);
    if (qk == 0) gact[rl] = act;
    __syncthreads();
    if (j < 16) {
      float iv  = gact[j];
      float fv  = gact[16 + j];
      float gv  = gact[32 + j];
      float ovv = gact[48 + j];
      cst = fv * cst + iv * gv;
      float h = ovv * tanh_f(cst);
      out16[(long)t * 512 + dir * 256 + 16 * p + j] = (_Float16)h;
      float hx = __shfl_xor(h, 1);
      if (!(j & 1)) {
        int idx = j >> 1;                       // 0..7
        unsigned hp = pack_h2(h, hx);
        h2v[8 * p + idx] = hp;                  // own slice for next step
        u64 tagged = ((u64)(unsigned)(s + 1) << 32) | (u64)hp;
        __hip_atomic_store(&mypay[((s + 1) & 1) * 8 + idx], tagged,
                           __ATOMIC_RELAXED, __HIP_MEMORY_SCOPE_AGENT);
      }
    }
    xc = xn_ + exv;
  }
}

// ---------------- final row softmax ----------------
__global__ __launch_bounds__(256) void softmax_rows(
    const float* __restrict__ logits, float* __restrict__ outp) {
  int t = blockIdx.x, tid = threadIdx.x;
  __shared__ float red[256];
  const float* lr = logits + (long)t * 4096;
  float v[16];
  float mx = -1e30f;
#pragma unroll
  for (int i = 0; i < 16; i++) { v[i] = lr[tid + 256 * i]; mx = fmaxf(mx, v[i]); }
  red[tid] = mx; __syncthreads();
  for (int s = 128; s > 0; s >>= 1) {
    if (tid < s) red[tid] = fmaxf(red[tid], red[tid + s]);
    __syncthreads();
  }
  mx = red[0]; __syncthreads();
  float sm = 0.f;
#pragma unroll
  for (int i = 0; i < 16; i++) { v[i] = __expf(v[i] - mx); sm += v[i]; }
  red[tid] = sm; __syncthreads();
  for (int s = 128; s > 0; s >>= 1) {
    if (tid < s) red[tid] += red[tid + s];
    __syncthreads();
  }
  float rz = 1.f / red[0];
#pragma unroll
  for (int i = 0; i < 16; i++) outp[(long)t * 4096 + tid + 256 * i] = v[i] * rz;
}

// ---------------- launch ----------------
extern "C" void kernel_launch(void* const* d_in, const int* in_sizes, int n_in,
                              void* d_out, int out_size, void* d_ws, size_t ws_size,
                              hipStream_t stream) {
  const float* c        = (const float*)d_in[0];
  const float* memory   = (const float*)d_in[1];
  const float* enc_Wih  = (const float*)d_in[2];
  const float* enc_Whh  = (const float*)d_in[3];
  const float* enc_bih  = (const float*)d_in[4];
  const float* enc_bhh  = (const float*)d_in[5];
  const float* cenc_Wih = (const float*)d_in[6];
  const float* cenc_Whh = (const float*)d_in[7];
  const float* cenc_bih = (const float*)d_in[8];
  const float* cenc_bhh = (const float*)d_in[9];
  const float* know_W   = (const float*)d_in[10];
  const float* know_b   = (const float*)d_in[11];
  const float* l0_Wih   = (const float*)d_in[12];
  const float* l0_Whh   = (const float*)d_in[13];
  const float* l0_bih   = (const float*)d_in[14];
  const float* l0_bhh   = (const float*)d_in[15];
  const float* l1_Wih   = (const float*)d_in[16];
  const float* l1_Whh   = (const float*)d_in[17];
  const float* l1_bih   = (const float*)d_in[18];
  const float* l1_bhh   = (const float*)d_in[19];
  const float* out_W    = (const float*)d_in[20];
  const float* out_b    = (const float*)d_in[21];

  float* ws = (float*)d_ws;
  float* outp = (float*)d_out;

  float* xgg   = ws;                  // 1,572,864   [T][768]
  float* cW    = ws + 1572864;        // 4,194,304   [T][2048] (ends 5,767,168)
  _Float16* l0out16 = (_Float16*)(ws + 5767168);  // 524,288 floats; dead before gemm4
  float* xg1   = ws + 7602176;        // 4,194,304   [T][2048]
  unsigned* wprep7 = (unsigned*)(ws + 11796480);  // 524,288 u32
  float* bcat  = ws + 12320768;       // 768
  float* bias0 = ws + 12321536;       // 2048
  float* bias1 = ws + 12323584;       // 2048
  float* u_vec = ws + 12325632;       // 256
  float* d_att = ws + 12325888;       // 8192
  float* p_att = ws + 12334080;       // 8192
  float* h_acc = ws + 12342272;       // 256
  float* o_vec = ws + 12342528;       // 1024
  float* ov    = ws + 12343552;       // 2048
  unsigned* wgru = (unsigned*)(ws + 13656320);      // 49,152 u32
  u64* payload = (u64*)(ws + 13705472);             // 1024 u64 (ends 13,707,520)
  float* logits = ws;                 // 8,388,608   aliases [0, 8.39M): all dead by gemm4

  _Float16* c16     = (_Float16*)(ws + 12345600);  // 1,048,576 floats; dead after gru_gemm
  _Float16* l1out16 = (_Float16*)(ws + 12345600);  // reuses c16 space; outside logits
  _Float16* wcat16  = (_Float16*)(ws + 7602176);   // in xg1: dead until gemm3 writes xg1
  _Float16* l0W16   = (_Float16*)(ws + 7995392);   // in xg1: used in gru_gemm < gemm3
  _Float16* l1W16   = (_Float16*)(ws + 13707520);  // 524,288 floats
  _Float16* outW16  = (_Float16*)(ws + 14231808);  // 1,048,576 floats (end 15,280,384)

  prep_kernel<<<512, 256, 0, stream>>>(c, enc_Wih, enc_bih, cenc_Wih, cenc_bih,
                                       enc_Whh, cenc_Whh,
                                       l0_Wih, l0_Whh, l1_Wih, l1_Whh, out_W,
                                       l0_bih, l0_bhh, l1_bih, l1_bhh,
                                       bcat, bias0, bias1, wprep7, wgru, payload,
                                       c16, wcat16, l0W16, l1W16, outW16);
  gemm_mfma<<<dim3(12, 32), 256, 0, stream>>>(c16, wcat16, bcat, xgg, 2048, 768, 1024);
  gru_gemm<<<1028, 384, 0, stream>>>(xgg, c, wgru, enc_Wih, enc_bih, enc_bhh,
                                     cenc_Wih, cenc_bih, cenc_bhh,
                                     u_vec, outp + kOUT_ELEMS,
                                     c16, l0W16, bias0, cW);
  attn_dots<<<256, 256, 0, stream>>>(memory, u_vec, d_att);
  attn_soft<<<1, 1024, 0, stream>>>(d_att, p_att, h_acc);
  attn_h<<<64, 256, 0, stream>>>(memory, p_att, h_acc);
  attn_o<<<8, 128, 0, stream>>>(u_vec, h_acc, know_W, know_b, o_vec);
  attn_ov<<<16, 128, 0, stream>>>(o_vec, l0_Wih, ov);
  lstm_cc16<<<128, 256, 0, stream>>>(wprep7, cW, ov, l0out16, payload);
  gemm_mfma<<<dim3(32, 32), 256, 0, stream>>>(l0out16, l1W16, bias1, xg1, 2048, 2048, 512);
  lstm_cc16<<<128, 256, 0, stream>>>(wprep7 + 262144, xg1, nullptr, l1out16, payload + 512);
  gemm_mfma<<<dim3(64, 32), 256, 0, stream>>>(l1out16, outW16, out_b, logits, 2048, 4096, 512);
  softmax_rows<<<2048, 256, 0, stream>>>(logits, outp);
}